// Round 7
// baseline (46.572 us; speedup 1.0000x reference)
//
#include <hip/hip_runtime.h>

#define NK 16       // cluster centers
#define ELEMS 7     // float4 elements per thread (n4 = 1792*256*7 exactly)

// Native clang vector type.
typedef float f32x4 __attribute__((ext_vector_type(4)));

// Bit-exact replica of the reference's per-element assignment for ANY t:
// scan k ascending, strict <  -> first index wins ties (jnp.argmin semantics).
__device__ __forceinline__ float argmin16(float t, const float* cen) {
    float best = 3.4e38f;
    float bc = 0.0f;
#pragma unroll
    for (int k = 0; k < NK; ++k) {
        float d = fabsf(t - cen[k]);
        bool p = d < best;
        best = p ? d : best;
        bc   = p ? cen[k] : bc;
    }
    return bc;
}

__global__ __launch_bounds__(256, 8) void lutfq_kernel(
    const f32x4* __restrict__ x,
    const float* __restrict__ scales,
    const float* __restrict__ centers,
    f32x4*       __restrict__ out,
    int n4)
{
    __shared__ float s_cen[NK];   // rounded centers (fallback + LUT build)
    __shared__ float s_lut[512];  // bucket -> center over u2 = 2t

    const int tid    = threadIdx.x;
    const int stride = gridDim.x * blockDim.x;
    const int i0     = blockIdx.x * blockDim.x + tid;

    // ---- Issue ALL streaming loads first: 7-deep MLP per wave. They fly
    // while the (VALU) prologue below executes; the barrier's vmcnt drain
    // is exactly "data arrived".
    f32x4 v[ELEMS];
#pragma unroll
    for (int u = 0; u < ELEMS; ++u) {
        int i = i0 + u * stride;
        if (i < n4) v[u] = x[i];
    }

    // Per-thread channels are grid-stride-invariant (stride % 64 == 0):
    // load the 4 owned scales once.
    const int c4 = (tid & 63) * 4;
    const f32x4 sv = *reinterpret_cast<const f32x4*>(&scales[c4]);
    float den[4], r256[4], so[4];
#pragma unroll
    for (int j = 0; j < 4; ++j) {
        den[j]  = sv[j] + 1e-8f;        // ref's denominator
        r256[j] = 256.0f / den[j];      // fast-path reciprocal (<=1 ulp on u2)
        so[j]   = sv[j] * 0.0078125f;   // s/128, exact
    }

    if (tid < NK) s_cen[tid] = rintf(centers[tid]);  // round-half-to-even
    __syncthreads();

    // 512-bucket LUT over u2 = 2t; integer centers -> decision midpoints are
    // half-integers = bucket edges -> constant on every bucket interior.
    // Buckets 0 / >=510 built at their LEFT edge (t = -128 / 127): provably
    // not midpoints of distinct integer centers in [-128,127], so the clip
    // masses are served exactly with no fallback.
    for (int ub = tid; ub < 512; ub += 256) {
        float t;
        if (ub == 0)        t = -128.0f;
        else if (ub >= 510) t = 127.0f;
        else                t = 0.5f * (float)(ub - 256) + 0.25f;
        s_lut[ub] = argmin16(t, s_cen);
    }
    __syncthreads();

    // ---- Process + store the 7 prefetched elements. No loop-carried deps.
#pragma unroll
    for (int u = 0; u < ELEMS; ++u) {
        int i = i0 + u * stride;
        if (i < n4) {
            f32x4 xv = v[u];
            f32x4 r;
#pragma unroll
            for (int j = 0; j < 4; ++j) {
                // u2 = 2 * clip(x/(s+eps)*128, -128, 127) as one mul + clamp.
                float u2 = xv[j] * r256[j];
                u2 = fminf(fmaxf(u2, -256.0f), 254.0f);

                float fl   = floorf(u2);      // exact
                float frac = u2 - fl;
                int   ub   = (int)fl + 256;   // 0..510

                float c = s_lut[ub];

                // Edge band (covers reciprocal's <=2^-15 error + ref's
                // rounded-distance tie band), minus the provably-safe clamp
                // rails: replay exact ref arithmetic. ~5e-4 of elements.
                bool band = (frac < 0x1p-12f) | (frac > 1.0f - 0x1p-12f);
                bool rail = (u2 == -256.0f) | (u2 == 254.0f);
                if (band && !rail) {
                    float t = (xv[j] / den[j]) * 128.0f;
                    t = fminf(fmaxf(t, -128.0f), 127.0f);
                    c = argmin16(t, s_cen);   // bit-exact ref replay
                }
                r[j] = c * so[j];   // c*(s/128) == (c/128)*s bit-exactly
            }
            out[i] = r;
        }
    }
}

extern "C" void kernel_launch(void* const* d_in, const int* in_sizes, int n_in,
                              void* d_out, int out_size, void* d_ws, size_t ws_size,
                              hipStream_t stream) {
    const float* x       = (const float*)d_in[0];
    const float* scales  = (const float*)d_in[1];
    const float* centers = (const float*)d_in[2];
    float* out = (float*)d_out;

    int n4 = out_size / 4;                       // 3,211,264 for this problem
    int per_block = 256 * ELEMS;                 // 1792 elements/block
    int blocks = (n4 + per_block - 1) / per_block;  // 1792 -> exactly 7 WGs/CU

    lutfq_kernel<<<blocks, 256, 0, stream>>>(
        (const f32x4*)x, scales, centers, (f32x4*)out, n4);
}

// Round 8
// 21.224 us; speedup vs baseline: 2.1943x; 2.1943x over previous
//
#include <hip/hip_runtime.h>

#define NK 16   // cluster centers
#define E  2    // f32x4 elements per thread (n4 = 6272 * 512 exactly)

typedef float f32x4 __attribute__((ext_vector_type(4)));

// Bit-exact replica of the reference's per-element assignment for ANY t:
// scan k ascending, strict <  -> first index wins ties (jnp.argmin semantics).
__device__ __forceinline__ float argmin16(float t, const float* cen) {
    float best = 3.4e38f;
    float bc = 0.0f;
#pragma unroll
    for (int k = 0; k < NK; ++k) {
        float d = fabsf(t - cen[k]);
        bool p = d < best;
        best = p ? d : best;
        bc   = p ? cen[k] : bc;
    }
    return bc;
}

// NO min-waves launch_bounds arg: R7's (256,8) cap spilled the prefetch
// registers to scratch (VGPR=32, WRITE_SIZE 2.8x). ~50 VGPR fits 8 waves/SIMD.
__global__ __launch_bounds__(256) void lutfq_kernel(
    const f32x4* __restrict__ x,
    const float* __restrict__ scales,
    const float* __restrict__ centers,
    f32x4*       __restrict__ out,
    int n4)
{
    __shared__ float s_lut[512];  // bucket -> center over u2 = 2t

    const int tid = threadIdx.x;
    // Block-contiguous: block owns [blockIdx*512, blockIdx*512+512).
    const int i0 = blockIdx.x * (256 * E) + tid;
    const int i1 = i0 + 256;

    // ---- Issue both streaming loads FIRST; the whole prologue below (rint,
    // scale math, LUT build) executes while they're in flight.
    f32x4 v0 = {0.f, 0.f, 0.f, 0.f}, v1 = {0.f, 0.f, 0.f, 0.f};
    if (i0 < n4) v0 = x[i0];
    if (i1 < n4) v1 = x[i1];

    // Rounded centers in (wave-uniform) registers.
    float cen[NK];
#pragma unroll
    for (int k = 0; k < NK; ++k) cen[k] = rintf(centers[k]);  // round-half-to-even

    // Per-thread channels are invariant: i0,i1 mod 64 == tid mod 64
    // (512 and 256 are multiples of 64). Load the 4 owned scales once.
    const int c4 = (tid & 63) * 4;
    const f32x4 sv = *reinterpret_cast<const f32x4*>(&scales[c4]);
    float den[4], r256[4], so[4];
#pragma unroll
    for (int j = 0; j < 4; ++j) {
        den[j]  = sv[j] + 1e-8f;        // ref's denominator
        r256[j] = 256.0f / den[j];      // fast-path reciprocal (<=1 ulp on u2)
        so[j]   = sv[j] * 0.0078125f;   // s/128, exact
    }

    // 512-bucket LUT over u2 = 2t; integer centers -> decision midpoints are
    // half-integers = bucket edges -> constant on bucket interiors. Buckets
    // 0 / >=510 built at their LEFT edge (t=-128/127): provably never a
    // midpoint of distinct integer centers in [-128,127] -> clip masses are
    // exact with no fallback.
    for (int ub = tid; ub < 512; ub += 256) {
        float t;
        if (ub == 0)        t = -128.0f;
        else if (ub >= 510) t = 127.0f;
        else                t = 0.5f * (float)(ub - 256) + 0.25f;
        s_lut[ub] = argmin16(t, cen);
    }
    __syncthreads();

    auto process = [&](f32x4 xv) -> f32x4 {
        f32x4 r;
#pragma unroll
        for (int j = 0; j < 4; ++j) {
            // u2 = 2 * clip(x/(s+eps)*128, -128, 127) as one mul + clamp.
            float u2 = xv[j] * r256[j];
            u2 = fminf(fmaxf(u2, -256.0f), 254.0f);

            float fl   = floorf(u2);      // exact
            float frac = u2 - fl;
            int   ub   = (int)fl + 256;   // 0..510

            float c = s_lut[ub];

            // Edge band (reciprocal's <=2^-15 error + ref's rounded-distance
            // tie band), minus the provably-safe clamp rails: replay exact
            // ref arithmetic. ~5e-4 of elements, exec-masked.
            bool band = (frac < 0x1p-12f) | (frac > 1.0f - 0x1p-12f);
            bool rail = (u2 == -256.0f) | (u2 == 254.0f);
            if (band && !rail) {
                float t = (xv[j] / den[j]) * 128.0f;
                t = fminf(fmaxf(t, -128.0f), 127.0f);
                c = argmin16(t, cen);                   // bit-exact ref replay
            }
            r[j] = c * so[j];   // c*(s/128) == (c/128)*s bit-exactly
        }
        return r;
    };

    f32x4 r0 = process(v0);
    f32x4 r1 = process(v1);
    if (i0 < n4) out[i0] = r0;
    if (i1 < n4) out[i1] = r1;
}

extern "C" void kernel_launch(void* const* d_in, const int* in_sizes, int n_in,
                              void* d_out, int out_size, void* d_ws, size_t ws_size,
                              hipStream_t stream) {
    const float* x       = (const float*)d_in[0];
    const float* scales  = (const float*)d_in[1];
    const float* centers = (const float*)d_in[2];
    float* out = (float*)d_out;

    int n4 = out_size / 4;                      // 3,211,264 here
    int per_block = 256 * E;                    // 512
    int blocks = (n4 + per_block - 1) / per_block;  // 6272: 3x backfill depth

    lutfq_kernel<<<blocks, 256, 0, stream>>>(
        (const f32x4*)x, scales, centers, (f32x4*)out, n4);
}